// Round 13
// baseline (193.812 us; speedup 1.0000x reference)
//
#include <hip/hip_runtime.h>
#include <math.h>

#define GAMMA 0.25f
constexpr int B_ = 8, Q_ = 64, N_ = 8192, K_ = 512, C_ = 256;

typedef __attribute__((ext_vector_type(8))) short bf16x8;
typedef __attribute__((ext_vector_type(4))) float f32x4;

static __device__ inline short f2bf(float x) {   // RNE float->bf16 bits
    union { float f; unsigned u; } v; v.f = x;
    unsigned r = (v.u + 0x7fffu + ((v.u >> 16) & 1u)) >> 16;
    return (short)r;
}
// pack trunc(lo),trunc(hi) bf16 into one dword via v_perm_b32 (1 instr)
static __device__ inline unsigned pack2(float lo, float hi) {
    return __builtin_amdgcn_perm(__float_as_uint(hi), __float_as_uint(lo), 0x07060302u);
}

// ---------------------------------------------------------------------------
// ONE block type: 1024 blocks x 64 items. Every wave carries BOTH legs so CE's
// VALU work (64 exps) executes inside the VQ load shadows.
//   CE: wave w sums exp over class quarter [64w,64w+64) (lane: g=items, c0=classes)
//   VQ: wave w owns codewords [128w,128w+128), 8 tiles x 8 MFMAs, depth-2 prefetch
// LDS floats: e2[0..512) | CE parts [512..768) | VQ minbuf [768..1024)
// ---------------------------------------------------------------------------
__global__ __launch_bounds__(256, 4) void fused_kernel(
    const float* __restrict__ ze, const float* __restrict__ emb,
    const float* __restrict__ qp, const int* __restrict__ tgt,
    float* __restrict__ out)
{
    __shared__ float smem[1024];
    const int tid  = threadIdx.x;
    const int lane = tid & 63;
    const int w    = tid >> 6;
    const int n16  = lane & 15;
    const int quad = lane >> 4;

    const int base = blockIdx.x * 64;            // 64-aligned => b uniform
    const int b    = base >> 13;
    const int n0   = base & (N_ - 1);
    const float* zb  = ze + (size_t)b * Q_ * N_;
    const float* qpb = qp + (size_t)b * C_ * N_;

    // --- phase 0: CE target gather (wave 1, lanes<16) — off critical path ---
    float xts[4] = {0.f, 0.f, 0.f, 0.f};
    if ((w == 1) && (lane < 16)) {
        #pragma unroll
        for (int j = 0; j < 4; ++j) {
            const int t = tgt[base + lane * 4 + j];
            xts[j] = qpb[(size_t)t * N_ + n0 + lane * 4 + j];
        }
    }

    // --- phase 1: A fragments (64 indep loads) + exact fp32 sum(z^2) ---
    bf16x8 afrag[4][2];
    float zsq = 0.f;
    #pragma unroll
    for (int u = 0; u < 4; ++u) {
        const int nn = n0 + u * 16 + n16;
        #pragma unroll
        for (int s = 0; s < 2; ++s) {
            #pragma unroll
            for (int j = 0; j < 8; ++j) {
                const int q = s * 32 + quad * 8 + j;
                const float x = zb[(size_t)q * N_ + nn];
                zsq = fmaf(x, x, zsq);
                afrag[u][s][j] = f2bf(-2.f * x);  // exact pow2 scale
            }
        }
    }

    // --- phase 2: CE loads (16 indep float4/lane, 1KB/instr per wave) ---
    const int g  = lane & 15;                    // item group (4 items)
    const int c0 = lane >> 4;                    // class subgroup
    const float* qpn = qpb + n0 + g * 4;
    const int cbase  = w * 64 + c0 * 16;
    float4 ce[16];
    #pragma unroll
    for (int j = 0; j < 16; ++j)
        ce[j] = *(const float4*)(qpn + (size_t)(cbase + j) * N_);

    // --- phase 3: e2 prologue into LDS (loads overlap CE exp work) ---
    for (int r = tid; r < K_; r += 256) {
        const float4* er = (const float4*)(emb + r * Q_);
        float s0 = 0.f, s1 = 0.f;
        #pragma unroll
        for (int i = 0; i < 16; i += 2) {
            const float4 a = er[i], c = er[i + 1];
            s0 = fmaf(a.x, a.x, fmaf(a.y, a.y, fmaf(a.z, a.z, fmaf(a.w, a.w, s0))));
            s1 = fmaf(c.x, c.x, fmaf(c.y, c.y, fmaf(c.z, c.z, fmaf(c.w, c.w, s1))));
        }
        smem[r] = s0 + s1;
    }

    // --- phase 4: CE exps (VALU work filling load shadows) + partial store ---
    {
        f32x4 acc = {0.f, 0.f, 0.f, 0.f};
        #pragma unroll
        for (int j = 0; j < 16; ++j) {
            acc[0] += __expf(ce[j].x); acc[1] += __expf(ce[j].y);
            acc[2] += __expf(ce[j].z); acc[3] += __expf(ce[j].w);
        }
        #pragma unroll
        for (int r = 0; r < 4; ++r) {            // sum over c0 (lane bits 4,5)
            acc[r] += __shfl_xor(acc[r], 16, 64);
            acc[r] += __shfl_xor(acc[r], 32, 64);
        }
        if (c0 == 0) ((f32x4*)(smem + 512))[w * 16 + g] = acc;
    }
    __syncthreads();                             // e2 + CE parts ready

    // --- phase 5: VQ B-loop, 8 tiles, depth-2 prefetch, 8 MFMAs/tile ---
    f32x4 best[4];
    #pragma unroll
    for (int u = 0; u < 4; ++u) best[u] = (f32x4){1e30f, 1e30f, 1e30f, 1e30f};

    const float* ebase = emb + (w * 128 + n16) * Q_ + quad * 8;
    float4 P0[4], P1[4];
    #pragma unroll
    for (int i = 0; i < 4; ++i) {
        P0[i] = *(const float4*)(ebase + (i & 1) * 4 + (i >> 1) * 32);
        P1[i] = *(const float4*)(ebase + 16 * Q_ + (i & 1) * 4 + (i >> 1) * 32);
    }

    #pragma unroll
    for (int t = 0; t < 8; ++t) {
        float4 cur[4];
        #pragma unroll
        for (int i = 0; i < 4; ++i) { cur[i] = P0[i]; P0[i] = P1[i]; }
        if (t < 6) {
            const float* np = ebase + (t + 2) * 16 * Q_;
            #pragma unroll
            for (int i = 0; i < 4; ++i)
                P1[i] = *(const float4*)(np + (i & 1) * 4 + (i >> 1) * 32);
        }

        union { bf16x8 v; unsigned u[4]; } B0, B1;
        B0.u[0] = pack2(cur[0].x, cur[0].y); B0.u[1] = pack2(cur[0].z, cur[0].w);
        B0.u[2] = pack2(cur[1].x, cur[1].y); B0.u[3] = pack2(cur[1].z, cur[1].w);
        B1.u[0] = pack2(cur[2].x, cur[2].y); B1.u[1] = pack2(cur[2].z, cur[2].w);
        B1.u[2] = pack2(cur[3].x, cur[3].y); B1.u[3] = pack2(cur[3].z, cur[3].w);

        const float p = smem[w * 128 + t * 16 + n16];   // broadcast/free ds_read
        const f32x4 ce2 = {p, p, p, p};
        #pragma unroll
        for (int u = 0; u < 4; ++u) {            // 4 independent MFMA chains
            f32x4 a = __builtin_amdgcn_mfma_f32_16x16x32_bf16(afrag[u][0], B0.v, ce2, 0, 0, 0);
            a       = __builtin_amdgcn_mfma_f32_16x16x32_bf16(afrag[u][1], B1.v, a,   0, 0, 0);
            #pragma unroll
            for (int r = 0; r < 4; ++r) best[u][r] = fminf(best[u][r], a[r]);
        }
    }

    // --- phase 6: VQ min over this wave's 16 cw columns; stash to LDS ---
    #pragma unroll
    for (int m = 1; m < 16; m <<= 1) {
        #pragma unroll
        for (int u = 0; u < 4; ++u) {
            #pragma unroll
            for (int r = 0; r < 4; ++r)
                best[u][r] = fminf(best[u][r], __shfl_xor(best[u][r], m, 64));
        }
    }
    if (n16 == 0) {                              // lanes 0,16,32,48
        #pragma unroll
        for (int u = 0; u < 4; ++u) {
            #pragma unroll
            for (int r = 0; r < 4; ++r)          // item = u*16 + quad*4 + r
                smem[768 + w * 64 + u * 16 + quad * 4 + r] = best[u][r];
        }
    }

    // --- CE finalize (wave 1; parts were ready at barrier 1) ---
    if (w == 1) {
        float loss = 0.f;
        if (lane < 16) {
            const f32x4* part = (const f32x4*)(smem + 512);
            const f32x4 tot = (part[lane] + part[16 + lane]) +
                              (part[32 + lane] + part[48 + lane]);
            #pragma unroll
            for (int j = 0; j < 4; ++j) loss += __logf(tot[j]) - xts[j];
        }
        #pragma unroll
        for (int off = 32; off > 0; off >>= 1) loss += __shfl_down(loss, off, 64);
        if (lane == 0) atomicAdd(out, loss);
    }

    __syncthreads();                             // minbuf ready
    if (w == 0) {
        const float mn = fminf(fminf(smem[768 + lane], smem[768 + 64 + lane]),
                               fminf(smem[768 + 128 + lane], smem[768 + 192 + lane]));
        float val = 1.25f * (mn + zsq);          // wave-0 zsq covers all 64 items
        #pragma unroll
        for (int off = 32; off > 0; off >>= 1) val += __shfl_down(val, off, 64);
        if (lane == 0) atomicAdd(out, val);
    }
}

extern "C" void kernel_launch(void* const* d_in, const int* in_sizes, int n_in,
                              void* d_out, int out_size, void* d_ws, size_t ws_size,
                              hipStream_t stream) {
    const float* ze  = (const float*)d_in[0];
    const float* emb = (const float*)d_in[1];
    const float* qp  = (const float*)d_in[2];
    const int*   tgt = (const int*)d_in[3];
    float* out = (float*)d_out;

    hipMemsetAsync(out, 0, sizeof(float), stream);

    fused_kernel<<<1024, 256, 0, stream>>>(ze, emb, qp, tgt, out);
}

// Round 14
// 134.251 us; speedup vs baseline: 1.4437x; 1.4437x over previous
//
#include <hip/hip_runtime.h>
#include <math.h>

#define GAMMA 0.25f
constexpr int B_ = 8, Q_ = 64, N_ = 8192, K_ = 512, C_ = 256;

typedef __attribute__((ext_vector_type(8))) short bf16x8;
typedef __attribute__((ext_vector_type(4))) short short4v;
typedef __attribute__((ext_vector_type(4))) float f32x4;

static __device__ inline short f2bf(float x) {   // RNE float->bf16 bits
    union { float f; unsigned u; } v; v.f = x;
    unsigned r = (v.u + 0x7fffu + ((v.u >> 16) & 1u)) >> 16;
    return (short)r;
}
static __device__ inline float bf2f(short h) {
    union { unsigned u; float f; } v; v.u = ((unsigned)(unsigned short)h) << 16;
    return v.f;
}

// ---------------------------------------------------------------------------
// prep: emb fp32[512][64] -> bf16 embB[512][64] + e2[k]=||bf16(emb_k)||^2 in ws.
// ---------------------------------------------------------------------------
__global__ __launch_bounds__(256) void prep_kernel(const float* __restrict__ emb,
                                                   short* __restrict__ embB,
                                                   float* __restrict__ e2g)
{
    const int r = blockIdx.x * 256 + threadIdx.x;
    if (r >= K_) return;
    const float4* src = (const float4*)(emb + r * Q_);
    short4v* dst = (short4v*)(embB + r * Q_);
    float s = 0.f;
    #pragma unroll
    for (int i = 0; i < 16; ++i) {
        const float4 v = src[i];
        short4v h;
        h[0] = f2bf(v.x); h[1] = f2bf(v.y); h[2] = f2bf(v.z); h[3] = f2bf(v.w);
        dst[i] = h;
        #pragma unroll
        for (int j = 0; j < 4; ++j) { const float a = bf2f(h[j]); s = fmaf(a, a, s); }
    }
    e2g[r] = s;
}

// ---------------------------------------------------------------------------
// Fused: 1024 blocks x 64 items; every wave carries BOTH legs.
//   CE: wave w sums exp over classes [64w,64w+64) (g=item grp, c0=class sub).
//   VQ: wave w owns codewords [128w,128w+128): 8 tiles x 8 MFMAs, B/e2 from ws.
// All loads issued in one stream (CE-A, A, CE-B, B, e2) -> single latency
// exposure; exp work executes inside the VQ-load shadow (vmcnt FIFO).
// LDS: [0..256) CE parts (f32x4[64]); [256..512) VQ minbuf. ONE barrier.
// ---------------------------------------------------------------------------
__global__ __launch_bounds__(256) void fused_kernel(
    const float* __restrict__ ze, const float* __restrict__ qp,
    const int* __restrict__ tgt, const short* __restrict__ embB,
    const float* __restrict__ e2g, float* __restrict__ out)
{
    __shared__ float smem[512];
    const int tid  = threadIdx.x;
    const int lane = tid & 63;
    const int w    = tid >> 6;
    const int n16  = lane & 15;
    const int quad = lane >> 4;
    const int g    = lane & 15;              // CE item group (4 items)
    const int c0   = lane >> 4;              // CE class subgroup

    const int base = blockIdx.x * 64;        // 64-aligned => b uniform
    const int b    = base >> 13;
    const int n0   = base & (N_ - 1);
    const float* zb  = ze + (size_t)b * Q_ * N_;
    const float* qpb = qp + (size_t)b * C_ * N_;
    const float* qpn = qpb + n0 + g * 4;
    const int cbase  = w * 64 + c0 * 16;

    // ---- issue CE chunk A (8 x float4, 1KB/instr per wave) ----
    float4 ceA[8];
    #pragma unroll
    for (int j = 0; j < 8; ++j)
        ceA[j] = *(const float4*)(qpn + (size_t)(cbase + j) * N_);

    // ---- issue A loads; convert to bf16(-2z) + exact fp32 zsq as they land ----
    bf16x8 afrag[4][2];
    float zsq = 0.f;
    #pragma unroll
    for (int u = 0; u < 4; ++u) {
        const int nn = n0 + u * 16 + n16;
        #pragma unroll
        for (int s = 0; s < 2; ++s) {
            #pragma unroll
            for (int j = 0; j < 8; ++j) {
                const int q = s * 32 + quad * 8 + j;
                const float x = zb[(size_t)q * N_ + nn];
                zsq = fmaf(x, x, zsq);
                afrag[u][s][j] = f2bf(-2.f * x);   // exact pow2 scale
            }
        }
    }

    // ---- issue CE chunk B ----
    float4 ceB[8];
    #pragma unroll
    for (int j = 0; j < 8; ++j)
        ceB[j] = *(const float4*)(qpn + (size_t)(cbase + 8 + j) * N_);

    // ---- issue ALL 8 B-tiles (bf16, 2 x 16B/lane/tile) + e2 (L1-hot) ----
    const short* bb = embB + (w * 128 + n16) * Q_ + quad * 8;
    bf16x8 Bv[8][2];
    float  e2v[8];
    #pragma unroll
    for (int t = 0; t < 8; ++t) {
        Bv[t][0] = *(const bf16x8*)(bb + t * 16 * Q_);
        Bv[t][1] = *(const bf16x8*)(bb + t * 16 * Q_ + 32);
        e2v[t]   = e2g[w * 128 + t * 16 + n16];
    }

    // ---- CE target gather (wave 1, lanes<16) ----
    float xts[4] = {0.f, 0.f, 0.f, 0.f};
    if ((w == 1) && (lane < 16)) {
        #pragma unroll
        for (int j = 0; j < 4; ++j) {
            const int t = tgt[base + lane * 4 + j];
            xts[j] = qpb[(size_t)t * N_ + n0 + lane * 4 + j];
        }
    }

    // ---- CE exp work (fills the VQ-load shadow) ----
    f32x4 acc = {0.f, 0.f, 0.f, 0.f};
    #pragma unroll
    for (int j = 0; j < 8; ++j) {
        acc[0] += __expf(ceA[j].x); acc[1] += __expf(ceA[j].y);
        acc[2] += __expf(ceA[j].z); acc[3] += __expf(ceA[j].w);
    }
    #pragma unroll
    for (int j = 0; j < 8; ++j) {
        acc[0] += __expf(ceB[j].x); acc[1] += __expf(ceB[j].y);
        acc[2] += __expf(ceB[j].z); acc[3] += __expf(ceB[j].w);
    }
    #pragma unroll
    for (int r = 0; r < 4; ++r) {            // sum over c0 (lane bits 4,5)
        acc[r] += __shfl_xor(acc[r], 16, 64);
        acc[r] += __shfl_xor(acc[r], 32, 64);
    }
    if (c0 == 0) ((f32x4*)smem)[w * 16 + g] = acc;

    // ---- VQ: 8 tiles back-to-back from registers ----
    f32x4 best[4];
    #pragma unroll
    for (int u = 0; u < 4; ++u) best[u] = (f32x4){1e30f, 1e30f, 1e30f, 1e30f};

    #pragma unroll
    for (int t = 0; t < 8; ++t) {
        const f32x4 ce2 = {e2v[t], e2v[t], e2v[t], e2v[t]};
        #pragma unroll
        for (int u = 0; u < 4; ++u) {        // 4 independent MFMA chains
            f32x4 a = __builtin_amdgcn_mfma_f32_16x16x32_bf16(afrag[u][0], Bv[t][0], ce2, 0, 0, 0);
            a       = __builtin_amdgcn_mfma_f32_16x16x32_bf16(afrag[u][1], Bv[t][1], a,   0, 0, 0);
            #pragma unroll
            for (int r = 0; r < 4; ++r) best[u][r] = fminf(best[u][r], a[r]);
        }
    }

    // ---- VQ min over this wave's 16 cw columns; stash per-item mins ----
    #pragma unroll
    for (int m = 1; m < 16; m <<= 1) {
        #pragma unroll
        for (int u = 0; u < 4; ++u) {
            #pragma unroll
            for (int r = 0; r < 4; ++r)
                best[u][r] = fminf(best[u][r], __shfl_xor(best[u][r], m, 64));
        }
    }
    if (n16 == 0) {                          // lanes 0,16,32,48
        #pragma unroll
        for (int u = 0; u < 4; ++u) {
            #pragma unroll
            for (int r = 0; r < 4; ++r)      // item = u*16 + quad*4 + r
                smem[256 + w * 64 + u * 16 + quad * 4 + r] = best[u][r];
        }
    }
    __syncthreads();                         // parts + minbuf ready

    // ---- CE finalize (wave 1) ----
    if (w == 1) {
        float loss = 0.f;
        if (lane < 16) {
            const f32x4* part = (const f32x4*)smem;
            const f32x4 tot = (part[lane] + part[16 + lane]) +
                              (part[32 + lane] + part[48 + lane]);
            #pragma unroll
            for (int j = 0; j < 4; ++j) loss += __logf(tot[j]) - xts[j];
        }
        #pragma unroll
        for (int off = 32; off > 0; off >>= 1) loss += __shfl_down(loss, off, 64);
        if (lane == 0) atomicAdd(out, loss);
    }

    // ---- VQ finalize (wave 0; zsq over wave 0 covers all 64 items) ----
    if (w == 0) {
        const float mn = fminf(fminf(smem[256 + lane], smem[256 + 64 + lane]),
                               fminf(smem[256 + 128 + lane], smem[256 + 192 + lane]));
        float val = 1.25f * (mn + zsq);
        #pragma unroll
        for (int off = 32; off > 0; off >>= 1) val += __shfl_down(val, off, 64);
        if (lane == 0) atomicAdd(out, val);
    }
}

extern "C" void kernel_launch(void* const* d_in, const int* in_sizes, int n_in,
                              void* d_out, int out_size, void* d_ws, size_t ws_size,
                              hipStream_t stream) {
    const float* ze  = (const float*)d_in[0];
    const float* emb = (const float*)d_in[1];
    const float* qp  = (const float*)d_in[2];
    const int*   tgt = (const int*)d_in[3];
    float* out = (float*)d_out;

    short* embB = (short*)d_ws;                                   // 64 KB
    float* e2g  = (float*)((char*)d_ws + K_ * Q_ * sizeof(short)); // +2 KB

    hipMemsetAsync(out, 0, sizeof(float), stream);

    prep_kernel<<<2, 256, 0, stream>>>(emb, embB, e2g);
    fused_kernel<<<1024, 256, 0, stream>>>(ze, qp, tgt, embB, e2g, out);
}